// Round 4
// baseline (264.008 us; speedup 1.0000x reference)
//
#include <hip/hip_runtime.h>

// SCVC: out[n, g*OG+o, p, q] = C[g,o]*x[n,g,p]*y[n,g,q]
//                              + wA[g,o,0]*x[n,g,p-1] + wA[g,o,1]*x[n,g,p+1]
//                              + wB[g,o,0]*y[n,g,q-1] + wB[g,o,1]*y[n,g,q+1]
// Shapes: N=8, G=8, OG=16, DX=DY=256. Output fp32 268 MB -> store-BW-bound.
// R4: (s,av) pairs interleaved in LDS (one ds_read_b64 broadcast per row),
// unroll 8, 4096 blocks (quarter-channel = 64 rows each) for more resident
// waves during store drain. Bench time is dominated by harness poison fills
// (~203 us of 1GiB ws + 268MB out); kernel itself estimated 45-60 us vs
// ~41-45 us write floor.

#define N_  8
#define G_  8
#define OG_ 16
#define DX_ 256
#define DY_ 256

typedef float vfloat4 __attribute__((ext_vector_type(4)));
typedef float vfloat2 __attribute__((ext_vector_type(2)));

__global__ __launch_bounds__(256) void scvc_kernel(
    const float* __restrict__ x,   // (N, G, DX)
    const float* __restrict__ y,   // (N, G, DY)
    const float* __restrict__ C,   // (G, OG)
    const float* __restrict__ wA,  // (G, OG, 2)
    const float* __restrict__ wB,  // (G, OG, 2)
    float* __restrict__ out)       // (N, G*OG, DX, DY)
{
    __shared__ vfloat2 sa[DX_];   // {C*x[p], wA0*x[p-1]+wA1*x[p+1]}
    __shared__ float ybuf[DY_];   // y[q]
    __shared__ float bbuf[DY_];   // wB0*y[q-1] + wB1*y[q+1]

    const int blk  = blockIdx.x;
    const int t    = blk >> 2;           // channel index 0 .. N*G*OG-1
    const int quad = blk & 3;            // which 64-row quarter
    const int n   = t / (G_ * OG_);
    const int rem = t % (G_ * OG_);
    const int g   = rem / OG_;
    const int o   = rem % OG_;

    const int tid = threadIdx.x;

    const int go = g * OG_ + o;
    const float co  = C[go];
    const float wa0 = wA[go * 2 + 0];
    const float wa1 = wA[go * 2 + 1];
    const float wb0 = wB[go * 2 + 0];
    const float wb1 = wB[go * 2 + 1];

    const float* xrow = x + (size_t)(n * G_ + g) * DX_;
    const float* yrow = y + (size_t)(n * G_ + g) * DY_;

    // One-time per-block staging (256 threads cover DX_=DY_=256).
    {
        float xv = xrow[tid];
        float xl = (tid > 0)       ? xrow[tid - 1] : 0.0f;
        float xr = (tid < DX_ - 1) ? xrow[tid + 1] : 0.0f;
        vfloat2 s2;
        s2.x = co * xv;
        s2.y = wa0 * xl + wa1 * xr;
        sa[tid] = s2;

        float yv = yrow[tid];
        float yl = (tid > 0)       ? yrow[tid - 1] : 0.0f;
        float yr = (tid < DY_ - 1) ? yrow[tid + 1] : 0.0f;
        ybuf[tid] = yv;
        bbuf[tid] = wb0 * yl + wb1 * yr;
    }
    __syncthreads();

    // Each thread owns a float4 at q = qv*4 (registers); wave lanes share p
    // -> sa[p] read is a wave-uniform ds_read_b64 broadcast.
    const int qv = tid & 63;
    const int pr = tid >> 6;
    const int pbase = quad * (DX_ / 4);

    const vfloat4 y4 = ((const vfloat4*)ybuf)[qv];
    const vfloat4 b4 = ((const vfloat4*)bbuf)[qv];

    float* obase = out + (size_t)t * (DX_ * DY_);

#pragma unroll 8
    for (int pb = 0; pb < DX_ / 4; pb += 4) {
        const int p  = pbase + pb + pr;
        const vfloat2 s2 = sa[p];
        const float s  = s2.x;
        const float av = s2.y;
        vfloat4 v;
        v.x = fmaf(s, y4.x, av + b4.x);
        v.y = fmaf(s, y4.y, av + b4.y);
        v.z = fmaf(s, y4.z, av + b4.z);
        v.w = fmaf(s, y4.w, av + b4.w);
        ((vfloat4*)(obase + (size_t)p * DY_))[qv] = v;
    }
}

extern "C" void kernel_launch(void* const* d_in, const int* in_sizes, int n_in,
                              void* d_out, int out_size, void* d_ws, size_t ws_size,
                              hipStream_t stream) {
    const float* x  = (const float*)d_in[0];
    const float* y  = (const float*)d_in[1];
    const float* C  = (const float*)d_in[2];
    const float* wA = (const float*)d_in[3];
    const float* wB = (const float*)d_in[4];
    float* out = (float*)d_out;

    const int nblocks = N_ * G_ * OG_ * 4;  // 4096
    scvc_kernel<<<nblocks, 256, 0, stream>>>(x, y, C, wA, wB, out);
}